// Round 8
// baseline (139.333 us; speedup 1.0000x reference)
//
#include <hip/hip_runtime.h>

// Varlen non-causal attention, qkv-packed (T,3,H,D) fp32 in/out.
// 3-kernel pipeline:
//  1) prep:    fp32 qkv -> bf16 Kb[h][t][d], Vtb[h][d][t]
//  2) main:    bf16 MFMA flash attention, TQ=64, split-K x2.
//              BARRIER-FREE main loop: K and V MFMA fragments are loaded
//              directly from global (16B/lane, contiguous) -- no LDS staging,
//              no __syncthreads. Only LDS use is the wave-private P round-trip.
//  3) combine: merge split-K partials (m,l,O) -> out

#define HEADS 8
#define DH 64
#define TQ 64
#define TK 64
#define PSTR 72
#define NSPLIT 2
#define NEG_BIG -1e30f
#define L2E 1.44269504088896340736f

using f32x4 = __attribute__((ext_vector_type(4))) float;
using s16x8 = __attribute__((ext_vector_type(8))) short;

__device__ inline unsigned short bf16b(float x) {
    union { float f; unsigned u; } c; c.f = x;
    unsigned r = c.u + 0x7fffu + ((c.u >> 16) & 1u);   // RNE
    return (unsigned short)(r >> 16);
}

#if __has_builtin(__builtin_amdgcn_cvt_pk_bf16_f32)
__device__ inline unsigned pk2(float a, float b) {
    auto v = __builtin_amdgcn_cvt_pk_bf16_f32(a, b);
    unsigned u; __builtin_memcpy(&u, &v, 4); return u;
}
#else
__device__ inline unsigned pk2(float a, float b) {
    return (unsigned)bf16b(a) | ((unsigned)bf16b(b) << 16);
}
#endif

// ---------------- pre-pass: convert + re-layout K,V ----------------
__global__ __launch_bounds__(256)
void prep_kernel(const float* __restrict__ qkv, unsigned short* __restrict__ Kb,
                 unsigned short* __restrict__ Vtb, int T) {
    __shared__ unsigned short Lt[64][PSTR];
    const int m = blockIdx.z + 1;          // 1 = K, 2 = V
    const int h = blockIdx.y, t0 = blockIdx.x * 64;
    const int tid = threadIdx.x, d8 = tid & 7, tr = tid >> 3;   // tr 0..31

    #pragma unroll
    for (int i = 0; i < 2; ++i) {
        int t = t0 + i * 32 + tr;
        int tc = t < T ? t : T - 1;
        const float* src = qkv + ((size_t)tc * 3 + m) * (HEADS * DH) + h * DH + d8 * 8;
        float4 a = *(const float4*)src;
        float4 b = *(const float4*)(src + 4);
        unsigned p0 = pk2(a.x, a.y), p1 = pk2(a.z, a.w);
        unsigned p2 = pk2(b.x, b.y), p3 = pk2(b.z, b.w);
        if (m == 2) {
            *(uint2*)&Lt[i * 32 + tr][d8 * 8]     = make_uint2(p0, p1);
            *(uint2*)&Lt[i * 32 + tr][d8 * 8 + 4] = make_uint2(p2, p3);
        } else if (t < T) {
            *(uint4*)(Kb + ((size_t)h * T + t) * DH + d8 * 8) = make_uint4(p0, p1, p2, p3);
        }
    }
    if (m == 2) {
        __syncthreads();
        const int d = tid >> 2, tg = tid & 3;
        #pragma unroll
        for (int p = 0; p < 2; ++p) {
            int G = tg + 4 * p;
            int td = t0 + G * 8;
            unsigned u[4];
            #pragma unroll
            for (int jj = 0; jj < 4; ++jj)
                u[jj] = (unsigned)Lt[G * 8 + 2 * jj][d] |
                        ((unsigned)Lt[G * 8 + 2 * jj + 1][d] << 16);
            if (td < T)
                *(uint4*)(Vtb + ((size_t)h * DH + d) * T + td) =
                    make_uint4(u[0], u[1], u[2], u[3]);
        }
    }
}

// ---------------- main flash kernel (barrier-free) ----------------
__global__ __launch_bounds__(256, 4)
void fa_main(const float* __restrict__ qkv, const unsigned short* __restrict__ Kb,
             const unsigned short* __restrict__ Vtb, const int* __restrict__ cu,
             int n_cu, int T, float* __restrict__ out,
             float* __restrict__ Opart, float* __restrict__ Mp, float* __restrict__ Lp) {
    __shared__ unsigned short Psh[TQ][PSTR];   // wave-private rows: no barriers

    const int tid = threadIdx.x;
    const int h = blockIdx.y, t0 = blockIdx.x * TQ;
    const int split = blockIdx.z, nsplit = gridDim.z;
    const int w = tid >> 6, lane = tid & 63, n15 = lane & 15, quad = lane >> 4;

    // ---- segment bounds ----
    int trow = t0 + w * 16 + n15; if (trow > T - 1) trow = T - 1;
    int lo, hi;
    { int s = 0; for (int j = 1; j < n_cu - 1; ++j) if (cu[j] <= trow) s = j;
      lo = cu[s]; hi = cu[s + 1]; }
    int kb_, ke;
    { int s = 0; for (int j = 1; j < n_cu - 1; ++j) if (cu[j] <= t0) s = j;
      kb_ = cu[s];
      int tl = t0 + TQ - 1; if (tl > T - 1) tl = T - 1;
      s = 0; for (int j = 1; j < n_cu - 1; ++j) if (cu[j] <= tl) s = j;
      ke = cu[s + 1]; }

    // ---- Q fragments: load fp32, fold 0.125, pack bf16 ----
    s16x8 qfrag[2];
    {
        int tc = t0 + w * 16 + n15; if (tc > T - 1) tc = T - 1;
        const float* qp = qkv + (size_t)tc * 3 * (HEADS * DH) + h * DH + quad * 8;
        #pragma unroll
        for (int kh = 0; kh < 2; ++kh) {
            float4 a = *(const float4*)(qp + kh * 32);
            float4 b = *(const float4*)(qp + kh * 32 + 4);
            unsigned u0 = pk2(a.x * 0.125f, a.y * 0.125f);
            unsigned u1 = pk2(a.z * 0.125f, a.w * 0.125f);
            unsigned u2 = pk2(b.x * 0.125f, b.y * 0.125f);
            unsigned u3 = pk2(b.z * 0.125f, b.w * 0.125f);
            uint4 uu = make_uint4(u0, u1, u2, u3);
            __builtin_memcpy(&qfrag[kh], &uu, 16);
        }
    }

    // ---- per-lane global fragment base pointers ----
    // K A-fragment (S^T): lane reads Kb[h][key = c0+nt*16+n15][quad*8 + kh*32 ..+7]
    const unsigned short* kp_base = Kb + ((size_t)h * T + n15) * DH + quad * 8;
    // V B-fragment (PV): lane reads Vtb[h][d = nt*16+n15][c0 + kh*32 + quad*8 ..+7]
    const unsigned short* vrow[4];
    #pragma unroll
    for (int nt = 0; nt < 4; ++nt)
        vrow[nt] = Vtb + ((size_t)h * DH + nt * 16 + n15) * T;

    f32x4 oacc[4];
    #pragma unroll
    for (int i = 0; i < 4; ++i) oacc[i] = (f32x4){0.f, 0.f, 0.f, 0.f};
    float m_ = NEG_BIG, l_ = 0.f;

    const int step = nsplit * TK;
    const int c0_start = (kb_ / TK) * TK + split * TK;

    for (int c0 = c0_start; c0 < ke; c0 += step) {
        // ---- K fragments: direct global b128 loads ----
        // kk is the base of a 16-row group: valid while kk+15 <= T-1.
        // (With 64-aligned c0 <= T-64 this clamp never fires; safety only.)
        s16x8 kf[4][2];
        #pragma unroll
        for (int nt = 0; nt < 4; ++nt) {
            int kk = c0 + nt * 16; if (kk > T - 16) kk = T - 16;
            const unsigned short* kp = kp_base + (size_t)kk * DH;
            kf[nt][0] = *(const s16x8*)kp;
            kf[nt][1] = *(const s16x8*)(kp + 32);
        }
        // ---- V fragments: direct global b128 loads (independent of P) ----
        s16x8 vf[4][2];
        #pragma unroll
        for (int kh = 0; kh < 2; ++kh) {
            int vb = c0 + kh * 32 + quad * 8; if (vb > T - 8) vb = T - 8;
            #pragma unroll
            for (int nt = 0; nt < 4; ++nt)
                vf[nt][kh] = *(const s16x8*)(vrow[nt] + vb);
        }

        // ---- S^T = K·Q^T : lane holds S[q=n15][key = nt*16 + quad*4 + reg] ----
        f32x4 sacc[4];
        #pragma unroll
        for (int nt = 0; nt < 4; ++nt) {
            f32x4 z = (f32x4){0.f, 0.f, 0.f, 0.f};
            z = __builtin_amdgcn_mfma_f32_16x16x32_bf16(kf[nt][0], qfrag[0], z, 0, 0, 0);
            z = __builtin_amdgcn_mfma_f32_16x16x32_bf16(kf[nt][1], qfrag[1], z, 0, 0, 0);
            sacc[nt] = z;
        }

        // ---- mask (boundary chunks only) ----
        if (!(c0 >= lo && c0 + TK <= hi)) {
            #pragma unroll
            for (int nt = 0; nt < 4; ++nt)
                #pragma unroll
                for (int reg = 0; reg < 4; ++reg) {
                    int key = c0 + nt * 16 + quad * 4 + reg;
                    bool valid = (key >= lo) && (key < hi);
                    sacc[nt][reg] = valid ? sacc[nt][reg] : NEG_BIG;
                }
        }

        // ---- online softmax (row = n15; reduce across quad lanes) ----
        float rm = NEG_BIG;
        #pragma unroll
        for (int nt = 0; nt < 4; ++nt)
            #pragma unroll
            for (int reg = 0; reg < 4; ++reg) rm = fmaxf(rm, sacc[nt][reg]);
        rm = fmaxf(rm, __shfl_xor(rm, 16));
        rm = fmaxf(rm, __shfl_xor(rm, 32));
        float mn = fmaxf(m_, rm);
        float alpha = exp2f((m_ - mn) * L2E);
        float mnl = mn * L2E;
        float rs = 0.f;
        #pragma unroll
        for (int nt = 0; nt < 4; ++nt) {
            float p0 = exp2f(fmaf(sacc[nt][0], L2E, -mnl));
            float p1 = exp2f(fmaf(sacc[nt][1], L2E, -mnl));
            float p2 = exp2f(fmaf(sacc[nt][2], L2E, -mnl));
            float p3 = exp2f(fmaf(sacc[nt][3], L2E, -mnl));
            rs += (p0 + p1) + (p2 + p3);
            *(uint2*)&Psh[w * 16 + n15][nt * 16 + quad * 4] =
                make_uint2(pk2(p0, p1), pk2(p2, p3));
        }
        rs += __shfl_xor(rs, 16);
        rs += __shfl_xor(rs, 32);
        l_ = fmaf(l_, alpha, rs);
        m_ = mn;
        #pragma unroll
        for (int reg = 0; reg < 4; ++reg) {
            float ar = __shfl(alpha, quad * 4 + reg);
            oacc[0][reg] *= ar; oacc[1][reg] *= ar;
            oacc[2][reg] *= ar; oacc[3][reg] *= ar;
        }

        // ---- PV: O += P·V (P via wave-private LDS; lgkmcnt orders it) ----
        s16x8 afr[2];
        afr[0] = *(const s16x8*)&Psh[w * 16 + n15][quad * 8];
        afr[1] = *(const s16x8*)&Psh[w * 16 + n15][32 + quad * 8];
        #pragma unroll
        for (int nt = 0; nt < 4; ++nt) {
            oacc[nt] = __builtin_amdgcn_mfma_f32_16x16x32_bf16(afr[0], vf[nt][0], oacc[nt], 0, 0, 0);
            oacc[nt] = __builtin_amdgcn_mfma_f32_16x16x32_bf16(afr[1], vf[nt][1], oacc[nt], 0, 0, 0);
        }
    }

    // ---- epilogue ----
    if (nsplit == 1) {
        #pragma unroll
        for (int reg = 0; reg < 4; ++reg) {
            float lr = __shfl(l_, quad * 4 + reg);
            float inv = 1.f / fmaxf(lr, 1e-30f);
            int t = t0 + w * 16 + quad * 4 + reg;
            if (t < T) {
                #pragma unroll
                for (int nt = 0; nt < 4; ++nt)
                    out[((size_t)t * HEADS + h) * DH + nt * 16 + n15] = oacc[nt][reg] * inv;
            }
        }
    } else {
        #pragma unroll
        for (int reg = 0; reg < 4; ++reg) {
            int t = t0 + w * 16 + quad * 4 + reg;
            if (t < T) {
                size_t base = (((size_t)split * T + t) * HEADS + h) * DH;
                #pragma unroll
                for (int nt = 0; nt < 4; ++nt)
                    Opart[base + nt * 16 + n15] = oacc[nt][reg];
            }
        }
        int tq = t0 + w * 16 + n15;
        if (quad == 0 && tq < T) {
            size_t mi = ((size_t)split * T + tq) * HEADS + h;
            Mp[mi] = m_; Lp[mi] = l_;
        }
    }
}

// ---------------- split-K combine ----------------
__global__ __launch_bounds__(256)
void fa_combine_kernel(const float* __restrict__ Opart, const float* __restrict__ Mp,
                       const float* __restrict__ Lp, float* __restrict__ out, int T) {
    int i4 = blockIdx.x * blockDim.x + threadIdx.x;
    int total = T * HEADS * (DH / 4);
    if (i4 >= total) return;
    int th = i4 / (DH / 4);
    int d4 = i4 - th * (DH / 4);
    size_t stride = (size_t)T * HEADS * DH;
    int mlstride = T * HEADS;
    float m[NSPLIT], l[NSPLIT];
    float M = NEG_BIG;
    #pragma unroll
    for (int s = 0; s < NSPLIT; ++s) {
        m[s] = Mp[(size_t)s * mlstride + th];
        l[s] = Lp[(size_t)s * mlstride + th];
        M = fmaxf(M, m[s]);
    }
    float L = 0.f, wgt[NSPLIT];
    #pragma unroll
    for (int s = 0; s < NSPLIT; ++s) {
        wgt[s] = exp2f((m[s] - M) * L2E);
        L = fmaf(l[s], wgt[s], L);
    }
    float inv = 1.f / fmaxf(L, 1e-30f);
    size_t off = (size_t)th * DH + 4 * d4;
    float4 o = make_float4(0.f, 0.f, 0.f, 0.f);
    #pragma unroll
    for (int s = 0; s < NSPLIT; ++s) {
        float4 a = *(const float4*)&Opart[(size_t)s * stride + off];
        float ws = wgt[s];
        o.x = fmaf(a.x, ws, o.x); o.y = fmaf(a.y, ws, o.y);
        o.z = fmaf(a.z, ws, o.z); o.w = fmaf(a.w, ws, o.w);
    }
    o.x *= inv; o.y *= inv; o.z *= inv; o.w *= inv;
    *(float4*)&out[off] = o;
}

extern "C" void kernel_launch(void* const* d_in, const int* in_sizes, int n_in,
                              void* d_out, int out_size, void* d_ws, size_t ws_size,
                              hipStream_t stream) {
    const float* qkv = (const float*)d_in[0];
    const int* cu    = (const int*)d_in[1];
    const int n_cu   = in_sizes[1];
    const int T      = in_sizes[0] / (3 * HEADS * DH);
    float* out       = (float*)d_out;

    size_t elems = (size_t)T * HEADS * DH;

    float* Opart = (float*)d_ws;                                  // NSPLIT*elems f32
    float* Mpp   = Opart + (size_t)NSPLIT * elems;                // NSPLIT*T*H f32
    float* Lpp   = Mpp + (size_t)NSPLIT * T * HEADS;
    unsigned short* Kb  = (unsigned short*)(Lpp + (size_t)NSPLIT * T * HEADS);
    unsigned short* Vtb = Kb + elems;

    int ptiles = (T + 63) / 64;
    dim3 pgrid(ptiles, HEADS, 2);
    prep_kernel<<<pgrid, 256, 0, stream>>>(qkv, Kb, Vtb, T);

    int tiles = (T + TQ - 1) / TQ;
    dim3 grid(tiles, HEADS, NSPLIT);
    fa_main<<<grid, 256, 0, stream>>>(qkv, Kb, Vtb, cu, n_cu, T, out, Opart, Mpp, Lpp);

    int total4 = T * HEADS * (DH / 4);
    fa_combine_kernel<<<(total4 + 255) / 256, 256, 0, stream>>>(Opart, Mpp, Lpp, out, T);
}